// Round 4
// baseline (1411.358 us; speedup 1.0000x reference)
//
#include <hip/hip_runtime.h>

#define BB 64
#define SS 2048
#define DD 128
#define HH 128

typedef float v2f __attribute__((ext_vector_type(2)));

// packed dual-fp32 FMA: acc.{lo,hi} += a.{lo,hi} * b.{lo,hi}
#define PKFMA(acc, a, b) \
    asm("v_pk_fma_f32 %0, %1, %2, %0" : "+v"(acc) : "v"(a), "v"(b))

__device__ __forceinline__ float fast_tanh(float x) {
    // tanh(x) = 1 - 2/(e^{2x}+1); exact at +-inf, ~1e-6 rel err
    float e = __expf(2.0f * x);
    return 1.0f - __fdividef(2.0f, e + 1.0f);
}

// ---------------------------------------------------------------------------
// Kernel 1: xproj = x @ Wx + b  (register-tiled fp32 GEMM) — unchanged (~50us)
// ---------------------------------------------------------------------------
__global__ __launch_bounds__(256, 2)
void xproj_kernel(const float* __restrict__ x, const float* __restrict__ W,
                  const float* __restrict__ bias, float* __restrict__ out) {
    __shared__ __align__(16) float4 wxs[64 * 32];   // Wx half: [64 k][128 j]
    __shared__ __align__(16) float4 xsw[128 * 16];  // x half:  [128 r][64 k], swizzled
    const int tid = threadIdx.x;
    const int tx  = tid & 15;
    const int ty  = tid >> 4;
    const long row0 = (long)blockIdx.x * 128;

    float acc[8][8];
#pragma unroll
    for (int i = 0; i < 8; ++i)
#pragma unroll
        for (int j = 0; j < 8; ++j) acc[i][j] = 0.f;

    for (int kh = 0; kh < 2; ++kh) {
        {
            const float4* wg = (const float4*)(W + kh * 64 * HH);
#pragma unroll
            for (int i = 0; i < 8; ++i) wxs[tid + i * 256] = wg[tid + i * 256];
        }
        {
#pragma unroll
            for (int i = 0; i < 8; ++i) {
                const int g  = tid + i * 256;
                const int r  = g >> 4;
                const int k4 = g & 15;
                const float4 v = ((const float4*)(x + (row0 + r) * DD + kh * 64))[k4];
                xsw[r * 16 + (k4 ^ ((r >> 3) & 7))] = v;
            }
        }
        __syncthreads();

        for (int k4 = 0; k4 < 16; ++k4) {
            float4 xa[8];
#pragma unroll
            for (int i = 0; i < 8; ++i)
                xa[i] = xsw[(ty * 8 + i) * 16 + (k4 ^ (ty & 7))];
            float4 wa[4][2];
#pragma unroll
            for (int kk = 0; kk < 4; ++kk) {
                wa[kk][0] = wxs[(k4 * 4 + kk) * 32 + tx * 2];
                wa[kk][1] = wxs[(k4 * 4 + kk) * 32 + tx * 2 + 1];
            }
#pragma unroll
            for (int i = 0; i < 8; ++i) {
#pragma unroll
                for (int kk = 0; kk < 4; ++kk) {
                    const float xv = (kk == 0) ? xa[i].x : (kk == 1) ? xa[i].y
                                   : (kk == 2) ? xa[i].z : xa[i].w;
                    acc[i][0] = fmaf(xv, wa[kk][0].x, acc[i][0]);
                    acc[i][1] = fmaf(xv, wa[kk][0].y, acc[i][1]);
                    acc[i][2] = fmaf(xv, wa[kk][0].z, acc[i][2]);
                    acc[i][3] = fmaf(xv, wa[kk][0].w, acc[i][3]);
                    acc[i][4] = fmaf(xv, wa[kk][1].x, acc[i][4]);
                    acc[i][5] = fmaf(xv, wa[kk][1].y, acc[i][5]);
                    acc[i][6] = fmaf(xv, wa[kk][1].z, acc[i][6]);
                    acc[i][7] = fmaf(xv, wa[kk][1].w, acc[i][7]);
                }
            }
        }
        __syncthreads();
    }

    const float4 b0 = ((const float4*)bias)[tx * 2];
    const float4 b1 = ((const float4*)bias)[tx * 2 + 1];
#pragma unroll
    for (int i = 0; i < 8; ++i) {
        const float4 o0 = make_float4(acc[i][0] + b0.x, acc[i][1] + b0.y,
                                      acc[i][2] + b0.z, acc[i][3] + b0.w);
        const float4 o1 = make_float4(acc[i][4] + b1.x, acc[i][5] + b1.y,
                                      acc[i][6] + b1.z, acc[i][7] + b1.w);
        float4* og = (float4*)(out + (row0 + ty * 8 + i) * HH);
        og[tx * 2]     = o0;
        og[tx * 2 + 1] = o1;
    }
}

// ---------------------------------------------------------------------------
// Kernel 2: recurrence v3 — 64 blocks x 128 threads (2 waves), one full
// output column per lane.
//  - lane j holds Wh[:,j] entirely in VGPRs (64 x v2f = 128 regs)
//  - full 128-deep dot per lane: 64 v_pk_fma_f32 in 4 independent chains
//    -> NO cross-lane reduce, NO divergent tanh section
//  - h reads are wave-uniform broadcast ds_read_b128 (conflict-free, cheap)
//  - barrier spans only 2 waves
//  - h written to LDS out-chunk, flushed to global every 16 steps
// ---------------------------------------------------------------------------
__global__ __launch_bounds__(128, 1)
void rnn_kernel(const float* __restrict__ W, float* __restrict__ out) {
    const int CH = 16;
    const int NC = SS / CH;

    __shared__ __align__(16) float xps[2][CH * HH];  // xproj chunks (2x8KB)
    __shared__ __align__(16) float hos[CH * HH];     // h out-chunk (8KB)
    __shared__ __align__(16) float hb[2][HH];        // double-buffered state

    const int b = blockIdx.x;
    const int j = threadIdx.x;       // 0..127: output column

    // Wh column j -> 64 packed float2 registers (coalesced loads across lanes)
    v2f wh2[64];
#pragma unroll
    for (int p = 0; p < 64; ++p) {
        v2f t;
        t.x = W[(long)(DD + 2 * p) * HH + j];
        t.y = W[(long)(DD + 2 * p + 1) * HH + j];
        wh2[p] = t;
    }

    float* const xbase = out + (long)b * SS * HH;

    hb[0][j] = 0.f;
    hb[1][j] = 0.f;

    // stage chunk 0 (512 float4, 4 per thread)
    {
        const float4* g = (const float4*)xbase;
        float4* l4 = (float4*)xps[0];
#pragma unroll
        for (int i = 0; i < 4; ++i) l4[j + i * 128] = g[j + i * 128];
    }
    __syncthreads();

    float4 pre[4];
    for (int c = 0; c < NC; ++c) {
        if (c + 1 < NC) {   // prefetch next xproj chunk into registers
            const float4* g = (const float4*)(xbase + (c + 1) * CH * HH);
#pragma unroll
            for (int i = 0; i < 4; ++i) pre[i] = g[j + i * 128];
        }
        const float* xp = xps[c & 1];
#pragma unroll
        for (int tt = 0; tt < CH; ++tt) {
            const int t = c * CH + tt;
            const float4* hv = (const float4*)hb[(t + 1) & 1];
            const float xpv = xp[tt * HH + j];

            v2f a0 = {0.f, 0.f}, a1 = {0.f, 0.f};
            v2f a2 = {0.f, 0.f}, a3 = {0.f, 0.f};
#pragma unroll
            for (int g2 = 0; g2 < 32; ++g2) {
                const float4 hq = hv[g2];      // uniform address -> broadcast
                v2f hlo; hlo.x = hq.x; hlo.y = hq.y;
                v2f hhi; hhi.x = hq.z; hhi.y = hq.w;
                if ((g2 & 1) == 0) {
                    PKFMA(a0, hlo, wh2[2 * g2]);
                    PKFMA(a1, hhi, wh2[2 * g2 + 1]);
                } else {
                    PKFMA(a2, hlo, wh2[2 * g2]);
                    PKFMA(a3, hhi, wh2[2 * g2 + 1]);
                }
            }
            const float s = ((a0.x + a0.y) + (a1.x + a1.y))
                          + ((a2.x + a2.y) + (a3.x + a3.y));
            const float h = fast_tanh(xpv + s);

            hb[t & 1][j]   = h;   // state for step t+1
            hos[tt * HH + j] = h; // output buffer (LDS)
            __syncthreads();      // 2-wave rendezvous, lgkm-only drain
        }
        // flush h chunk to global (overwrites consumed xproj in place)
        {
            float4* hg = (float4*)(xbase + c * CH * HH);
            const float4* hl = (const float4*)hos;
#pragma unroll
            for (int i = 0; i < 4; ++i) hg[j + i * 128] = hl[j + i * 128];
        }
        if (c + 1 < NC) {   // commit prefetched chunk
            float4* l4 = (float4*)xps[(c + 1) & 1];
#pragma unroll
            for (int i = 0; i < 4; ++i) l4[j + i * 128] = pre[i];
        }
        __syncthreads();
    }

    // final hidden state
    out[(long)BB * SS * HH + b * HH + j] = hb[1][j];
}

extern "C" void kernel_launch(void* const* d_in, const int* in_sizes, int n_in,
                              void* d_out, int out_size, void* d_ws, size_t ws_size,
                              hipStream_t stream) {
    const float* x    = (const float*)d_in[0];
    const float* W    = (const float*)d_in[1];
    const float* bias = (const float*)d_in[2];
    float* out = (float*)d_out;

    xproj_kernel<<<dim3((BB * SS) / 128), dim3(256), 0, stream>>>(x, W, bias, out);
    rnn_kernel<<<dim3(BB), dim3(128), 0, stream>>>(W, out);
}

// Round 5
// 956.989 us; speedup vs baseline: 1.4748x; 1.4748x over previous
//
#include <hip/hip_runtime.h>

#define BB 64
#define SS 2048
#define DD 128
#define HH 128

__device__ __forceinline__ float fast_tanh(float x) {
    // tanh(x) = 1 - 2/(e^{2x}+1); exact at +-inf, ~1e-6 rel err
    float e = __expf(2.0f * x);
    return 1.0f - __fdividef(2.0f, e + 1.0f);
}

// quad-local butterfly ALLreduce (lanes 4g..4g+3) via DPP quad_perm — VALU
// only; after both stages every lane of the quad holds the full sum.
__device__ __forceinline__ float quad_allreduce(float v) {
    int a = __builtin_amdgcn_update_dpp(0, __float_as_int(v), 0xB1, 0xF, 0xF, true); // [1,0,3,2] xor1
    v += __int_as_float(a);
    int c = __builtin_amdgcn_update_dpp(0, __float_as_int(v), 0x4E, 0xF, 0xF, true); // [2,3,0,1] xor2
    v += __int_as_float(c);
    return v;
}

// ---------------------------------------------------------------------------
// Kernel 1: xproj = x @ Wx + b  (register-tiled fp32 GEMM) — unchanged (~54us)
// ---------------------------------------------------------------------------
__global__ __launch_bounds__(256, 2)
void xproj_kernel(const float* __restrict__ x, const float* __restrict__ W,
                  const float* __restrict__ bias, float* __restrict__ out) {
    __shared__ __align__(16) float4 wxs[64 * 32];   // Wx half: [64 k][128 j]
    __shared__ __align__(16) float4 xsw[128 * 16];  // x half:  [128 r][64 k], swizzled
    const int tid = threadIdx.x;
    const int tx  = tid & 15;
    const int ty  = tid >> 4;
    const long row0 = (long)blockIdx.x * 128;

    float acc[8][8];
#pragma unroll
    for (int i = 0; i < 8; ++i)
#pragma unroll
        for (int j = 0; j < 8; ++j) acc[i][j] = 0.f;

    for (int kh = 0; kh < 2; ++kh) {
        {
            const float4* wg = (const float4*)(W + kh * 64 * HH);
#pragma unroll
            for (int i = 0; i < 8; ++i) wxs[tid + i * 256] = wg[tid + i * 256];
        }
        {
#pragma unroll
            for (int i = 0; i < 8; ++i) {
                const int g  = tid + i * 256;
                const int r  = g >> 4;
                const int k4 = g & 15;
                const float4 v = ((const float4*)(x + (row0 + r) * DD + kh * 64))[k4];
                xsw[r * 16 + (k4 ^ ((r >> 3) & 7))] = v;
            }
        }
        __syncthreads();

        for (int k4 = 0; k4 < 16; ++k4) {
            float4 xa[8];
#pragma unroll
            for (int i = 0; i < 8; ++i)
                xa[i] = xsw[(ty * 8 + i) * 16 + (k4 ^ (ty & 7))];
            float4 wa[4][2];
#pragma unroll
            for (int kk = 0; kk < 4; ++kk) {
                wa[kk][0] = wxs[(k4 * 4 + kk) * 32 + tx * 2];
                wa[kk][1] = wxs[(k4 * 4 + kk) * 32 + tx * 2 + 1];
            }
#pragma unroll
            for (int i = 0; i < 8; ++i) {
#pragma unroll
                for (int kk = 0; kk < 4; ++kk) {
                    const float xv = (kk == 0) ? xa[i].x : (kk == 1) ? xa[i].y
                                   : (kk == 2) ? xa[i].z : xa[i].w;
                    acc[i][0] = fmaf(xv, wa[kk][0].x, acc[i][0]);
                    acc[i][1] = fmaf(xv, wa[kk][0].y, acc[i][1]);
                    acc[i][2] = fmaf(xv, wa[kk][0].z, acc[i][2]);
                    acc[i][3] = fmaf(xv, wa[kk][0].w, acc[i][3]);
                    acc[i][4] = fmaf(xv, wa[kk][1].x, acc[i][4]);
                    acc[i][5] = fmaf(xv, wa[kk][1].y, acc[i][5]);
                    acc[i][6] = fmaf(xv, wa[kk][1].z, acc[i][6]);
                    acc[i][7] = fmaf(xv, wa[kk][1].w, acc[i][7]);
                }
            }
        }
        __syncthreads();
    }

    const float4 b0 = ((const float4*)bias)[tx * 2];
    const float4 b1 = ((const float4*)bias)[tx * 2 + 1];
#pragma unroll
    for (int i = 0; i < 8; ++i) {
        const float4 o0 = make_float4(acc[i][0] + b0.x, acc[i][1] + b0.y,
                                      acc[i][2] + b0.z, acc[i][3] + b0.w);
        const float4 o1 = make_float4(acc[i][4] + b1.x, acc[i][5] + b1.y,
                                      acc[i][6] + b1.z, acc[i][7] + b1.w);
        float4* og = (float4*)(out + (row0 + ty * 8 + i) * HH);
        og[tx * 2]     = o0;
        og[tx * 2 + 1] = o1;
    }
}

// ---------------------------------------------------------------------------
// Kernel 2: recurrence v4 — 64 blocks x 512 threads (8 waves).
// KEY CHANGE: per-lane Wh shrunk to 32 floats so the allocator keeps it in
// VGPRs (R1/R3/R4 all parked the 64-128 float Wh arrays out of registers —
// VGPR_Count 52-84 < array size — and per-step re-reads dominated).
//   thread tid: col j = tid>>2, k-slice s4 = tid&3 (32 k's each)
//   32 fmaf/step/lane, DPP quad-ALLreduce (no divergent tanh),
//   bank-staggered h reads (0 conflicts, per R3), LDS-only step loop.
// ---------------------------------------------------------------------------
__global__ __launch_bounds__(512, 1)
void rnn_kernel(const float* __restrict__ W, float* __restrict__ out) {
    const int CH = 16;
    const int NC = SS / CH;

    __shared__ __align__(16) float xps[2][CH * HH];  // xproj chunks (2x8KB)
    __shared__ __align__(16) float hos[CH * HH];     // h out-chunk (8KB)
    __shared__ __align__(16) float hb[2][HH];        // double-buffered state

    const int b   = blockIdx.x;
    const int tid = threadIdx.x;
    const int j   = tid >> 2;     // 0..127: output column
    const int s4  = tid & 3;      // k-slice: k in [32*s4, 32*s4+32)

    // Wh fragment (32 floats), pre-rotated to match staggered read order
    float wh[32];
#pragma unroll
    for (int p = 0; p < 32; ++p) {
        const int q = p >> 2, u = p & 3;
        const int k = 32 * s4 + (((q + 2 * s4) & 7) << 2) + u;
        wh[p] = W[(long)(DD + k) * HH + j];
    }

    float* const xbase = out + (long)b * SS * HH;

    if (tid < 128) { hb[0][tid] = 0.f; hb[1][tid] = 0.f; }

    // stage chunk 0 (512 float4, 1 per thread)
    {
        const float4* g = (const float4*)xbase;
        ((float4*)xps[0])[tid] = g[tid];
    }
    __syncthreads();

    float4 pre;
    for (int c = 0; c < NC; ++c) {
        if (c + 1 < NC) {   // prefetch next xproj chunk into a register
            pre = ((const float4*)(xbase + (c + 1) * CH * HH))[tid];
        }
        const float* xp = xps[c & 1];
#pragma unroll
        for (int tt = 0; tt < CH; ++tt) {
            const int t = c * CH + tt;
            const float4* hv = (const float4*)hb[(t + 1) & 1];
            float a0 = 0.f, a1 = 0.f, a2 = 0.f, a3 = 0.f;
#pragma unroll
            for (int q = 0; q < 8; ++q) {
                const float4 hq = hv[8 * s4 + ((q + 2 * s4) & 7)]; // bank-staggered
                a0 = fmaf(hq.x, wh[4*q+0], a0);
                a1 = fmaf(hq.y, wh[4*q+1], a1);
                a2 = fmaf(hq.z, wh[4*q+2], a2);
                a3 = fmaf(hq.w, wh[4*q+3], a3);
            }
            float s = (a0 + a1) + (a2 + a3);
            s = quad_allreduce(s);             // all 4 lanes get the sum

            const float h = fast_tanh(xp[tt * HH + j] + s);  // undiverged
            if (s4 == 0) hb[t & 1][j] = h;        // state for step t+1
            if (s4 == 1) hos[tt * HH + j] = h;    // output buffer (LDS)
            __syncthreads();   // lgkm-only drain (no vmem in step loop)
        }
        // flush h chunk to global (overwrites consumed xproj in place)
        {
            ((float4*)(xbase + c * CH * HH))[tid] = ((const float4*)hos)[tid];
        }
        if (c + 1 < NC) {   // commit prefetched chunk
            ((float4*)xps[(c + 1) & 1])[tid] = pre;
        }
        __syncthreads();
    }

    // final hidden state
    if (tid < 128) {
        out[(long)BB * SS * HH + b * HH + tid] = hb[1][tid];
    }
}

extern "C" void kernel_launch(void* const* d_in, const int* in_sizes, int n_in,
                              void* d_out, int out_size, void* d_ws, size_t ws_size,
                              hipStream_t stream) {
    const float* x    = (const float*)d_in[0];
    const float* W    = (const float*)d_in[1];
    const float* bias = (const float*)d_in[2];
    float* out = (float*)d_out;

    xproj_kernel<<<dim3((BB * SS) / 128), dim3(256), 0, stream>>>(x, W, bias, out);
    rnn_kernel<<<dim3(BB), dim3(512), 0, stream>>>(W, out);
}

// Round 6
// 698.959 us; speedup vs baseline: 2.0192x; 1.3692x over previous
//
#include <hip/hip_runtime.h>

#define BB 64
#define SS 2048
#define DD 128
#define HH 128

typedef float v2f __attribute__((ext_vector_type(2)));

// packed dual-fp32 FMA: acc.{lo,hi} += a.{lo,hi} * b.{lo,hi}
#define PKFMA(acc, a, b) \
    asm("v_pk_fma_f32 %0, %1, %2, %0" : "+v"(acc) : "v"(a), "v"(b))

__device__ __forceinline__ float fast_tanh(float x) {
    // tanh(x) = 1 - 2/(e^{2x}+1); exact at +-inf, ~1e-6 rel err
    float e = __expf(2.0f * x);
    return 1.0f - __fdividef(2.0f, e + 1.0f);
}

// quad-local butterfly ALLreduce (lanes 4g..4g+3) via DPP quad_perm — VALU
// only; after both stages every lane of the quad holds the full sum.
__device__ __forceinline__ float quad_allreduce(float v) {
    int a = __builtin_amdgcn_update_dpp(0, __float_as_int(v), 0xB1, 0xF, 0xF, true); // [1,0,3,2] xor1
    v += __int_as_float(a);
    int c = __builtin_amdgcn_update_dpp(0, __float_as_int(v), 0x4E, 0xF, 0xF, true); // [2,3,0,1] xor2
    v += __int_as_float(c);
    return v;
}

// ---------------------------------------------------------------------------
// Kernel 1: xproj = x @ Wx + b  (register-tiled fp32 GEMM) — unchanged (~54us)
// ---------------------------------------------------------------------------
__global__ __launch_bounds__(256, 2)
void xproj_kernel(const float* __restrict__ x, const float* __restrict__ W,
                  const float* __restrict__ bias, float* __restrict__ out) {
    __shared__ __align__(16) float4 wxs[64 * 32];   // Wx half: [64 k][128 j]
    __shared__ __align__(16) float4 xsw[128 * 16];  // x half:  [128 r][64 k], swizzled
    const int tid = threadIdx.x;
    const int tx  = tid & 15;
    const int ty  = tid >> 4;
    const long row0 = (long)blockIdx.x * 128;

    float acc[8][8];
#pragma unroll
    for (int i = 0; i < 8; ++i)
#pragma unroll
        for (int j = 0; j < 8; ++j) acc[i][j] = 0.f;

    for (int kh = 0; kh < 2; ++kh) {
        {
            const float4* wg = (const float4*)(W + kh * 64 * HH);
#pragma unroll
            for (int i = 0; i < 8; ++i) wxs[tid + i * 256] = wg[tid + i * 256];
        }
        {
#pragma unroll
            for (int i = 0; i < 8; ++i) {
                const int g  = tid + i * 256;
                const int r  = g >> 4;
                const int k4 = g & 15;
                const float4 v = ((const float4*)(x + (row0 + r) * DD + kh * 64))[k4];
                xsw[r * 16 + (k4 ^ ((r >> 3) & 7))] = v;
            }
        }
        __syncthreads();

        for (int k4 = 0; k4 < 16; ++k4) {
            float4 xa[8];
#pragma unroll
            for (int i = 0; i < 8; ++i)
                xa[i] = xsw[(ty * 8 + i) * 16 + (k4 ^ (ty & 7))];
            float4 wa[4][2];
#pragma unroll
            for (int kk = 0; kk < 4; ++kk) {
                wa[kk][0] = wxs[(k4 * 4 + kk) * 32 + tx * 2];
                wa[kk][1] = wxs[(k4 * 4 + kk) * 32 + tx * 2 + 1];
            }
#pragma unroll
            for (int i = 0; i < 8; ++i) {
#pragma unroll
                for (int kk = 0; kk < 4; ++kk) {
                    const float xv = (kk == 0) ? xa[i].x : (kk == 1) ? xa[i].y
                                   : (kk == 2) ? xa[i].z : xa[i].w;
                    acc[i][0] = fmaf(xv, wa[kk][0].x, acc[i][0]);
                    acc[i][1] = fmaf(xv, wa[kk][0].y, acc[i][1]);
                    acc[i][2] = fmaf(xv, wa[kk][0].z, acc[i][2]);
                    acc[i][3] = fmaf(xv, wa[kk][0].w, acc[i][3]);
                    acc[i][4] = fmaf(xv, wa[kk][1].x, acc[i][4]);
                    acc[i][5] = fmaf(xv, wa[kk][1].y, acc[i][5]);
                    acc[i][6] = fmaf(xv, wa[kk][1].z, acc[i][6]);
                    acc[i][7] = fmaf(xv, wa[kk][1].w, acc[i][7]);
                }
            }
        }
        __syncthreads();
    }

    const float4 b0 = ((const float4*)bias)[tx * 2];
    const float4 b1 = ((const float4*)bias)[tx * 2 + 1];
#pragma unroll
    for (int i = 0; i < 8; ++i) {
        const float4 o0 = make_float4(acc[i][0] + b0.x, acc[i][1] + b0.y,
                                      acc[i][2] + b0.z, acc[i][3] + b0.w);
        const float4 o1 = make_float4(acc[i][4] + b1.x, acc[i][5] + b1.y,
                                      acc[i][6] + b1.z, acc[i][7] + b1.w);
        float4* og = (float4*)(out + (row0 + ty * 8 + i) * HH);
        og[tx * 2]     = o0;
        og[tx * 2 + 1] = o1;
    }
}

// ---------------------------------------------------------------------------
// Kernel 2: recurrence v5 — 64 blocks x 256 threads (4 waves), J=2 cols/lane.
//  Model from R1-R5: per-step ~= F(450) + 7cy * DS_instrs. J=2 halves the
//  column-read DS count (8 b128 serve 2 cols); xproj LDS staging deleted
//  (per-thread register chunks, owner-lane adds xp pre-reduce); pk_fma pairs
//  along K so float4 halves feed it directly; wh=64 floats/lane (<256 total,
//  no spill); tanh on all lanes; state/output writes from disjoint lanes.
// ---------------------------------------------------------------------------
__global__ __launch_bounds__(256, 1)
void rnn_kernel(const float* __restrict__ W, float* __restrict__ out) {
    const int CH = 16;
    const int NC = SS / CH;

    __shared__ __align__(16) float hos[CH * HH];   // h out-chunk (8KB)
    __shared__ __align__(16) float hb[2][HH];      // double-buffered state

    const int b    = blockIdx.x;
    const int tid  = threadIdx.x;
    const int w    = tid >> 6;
    const int lane = tid & 63;
    const int s    = lane & 3;      // k-slice: k in [32s, 32s+32)
    const int jj   = lane >> 2;     // 0..15
    const int j0   = w * 32 + 2 * jj;   // column pair (j0, j0+1)

    // Wh fragments, paired along K, quad-staggered to match read order:
    // read r -> h4 = h[32s + 4*rot(r) .. +4), rot(r) = (r+2s)&7
    // whA[2r]   pairs (k0,k0+1) for col j0;  whA[2r+1] pairs (k0+2,k0+3)
    v2f whA[16], whB[16];
#pragma unroll
    for (int m = 0; m < 16; ++m) {
        const int r = m >> 1, u = (m & 1) * 2;
        const int k = 32 * s + (((r + 2 * s) & 7) << 2) + u;
        const float* w0 = W + (long)(DD + k) * HH;
        const float* w1 = W + (long)(DD + k + 1) * HH;
        v2f a; a.x = w0[j0];     a.y = w1[j0];     whA[m] = a;
        v2f bb; bb.x = w0[j0 + 1]; bb.y = w1[j0 + 1]; whB[m] = bb;
    }

    float* const xbase = out + (long)b * SS * HH;

    if (tid < 128) { hb[0][tid] = 0.f; hb[1][tid] = 0.f; }

    // xpc: this thread's xproj values — it OWNS steps tt = 4s..4s+3 of the
    // chunk, cols (j0, j0+1) as one v2f each. Loaded straight from global.
    v2f xpc[4];
    {
        const float* g = xbase + (4 * s) * HH + j0;
#pragma unroll
        for (int i = 0; i < 4; ++i) xpc[i] = *(const v2f*)(g + i * HH);
    }
    __syncthreads();

    for (int c = 0; c < NC; ++c) {
#pragma unroll
        for (int tt = 0; tt < CH; ++tt) {
            const int t = c * CH + tt;
            const float4* hv = (const float4*)hb[(t + 1) & 1];

            v2f A0 = {0.f, 0.f}, A1 = {0.f, 0.f};
            v2f B0 = {0.f, 0.f}, B1 = {0.f, 0.f};
#pragma unroll
            for (int r = 0; r < 8; ++r) {
                const float4 h4 = hv[8 * s + ((r + 2 * s) & 7)]; // staggered, 0-conflict
                v2f hlo; hlo.x = h4.x; hlo.y = h4.y;
                v2f hhi; hhi.x = h4.z; hhi.y = h4.w;
                PKFMA(A0, hlo, whA[2 * r]);
                PKFMA(A1, hhi, whA[2 * r + 1]);
                PKFMA(B0, hlo, whB[2 * r]);
                PKFMA(B1, hhi, whB[2 * r + 1]);
            }
            const v2f SA = A0 + A1;            // v_pk_add
            const v2f SB = B0 + B1;
            float fA = SA.x + SA.y;
            float fB = SB.x + SB.y;
            // owner lane folds xproj in BEFORE the allreduce (distributes free)
            const bool own = (s == (tt >> 2));
            fA += own ? xpc[tt & 3].x : 0.f;
            fB += own ? xpc[tt & 3].y : 0.f;
            fA = quad_allreduce(fA);
            fB = quad_allreduce(fB);

            const float hx = (s < 2) ? fA : fB;
            const float h  = fast_tanh(hx);     // all 64 lanes useful
            const int col  = j0 + (s >> 1);
            if ((s & 1) == 0) hb[t & 1][col] = h;        // state (s=0,2)
            else              hos[tt * HH + col] = h;    // output (s=1,3)
            __syncthreads();
        }

        // flush h chunk to global (overwrites consumed xproj rows in place)
        {
            float4* hg = (float4*)(xbase + c * CH * HH);
            const float4* hl = (const float4*)hos;
            hg[tid]       = hl[tid];
            hg[tid + 256] = hl[tid + 256];
        }
        // load next chunk's xproj into registers (rows disjoint from flush)
        if (c + 1 < NC) {
            const float* g = xbase + (c + 1) * CH * HH + (4 * s) * HH + j0;
#pragma unroll
            for (int i = 0; i < 4; ++i) xpc[i] = *(const v2f*)(g + i * HH);
        }
        __syncthreads();   // protects hos reuse (flush-read vs next writes)
    }

    // final hidden state
    if (tid < 128) {
        out[(long)BB * SS * HH + b * HH + tid] = hb[1][tid];
    }
}

extern "C" void kernel_launch(void* const* d_in, const int* in_sizes, int n_in,
                              void* d_out, int out_size, void* d_ws, size_t ws_size,
                              hipStream_t stream) {
    const float* x    = (const float*)d_in[0];
    const float* W    = (const float*)d_in[1];
    const float* bias = (const float*)d_in[2];
    float* out = (float*)d_out;

    xproj_kernel<<<dim3((BB * SS) / 128), dim3(256), 0, stream>>>(x, W, bias, out);
    rnn_kernel<<<dim3(BB), dim3(256), 0, stream>>>(W, out);
}